// Round 9
// baseline (428.511 us; speedup 1.0000x reference)
//
#include <hip/hip_runtime.h>
#include <hip/hip_bf16.h>
#include <math.h>

// ---------------------------------------------------------------------------
// GraphClassifiction: conv1d(k=3)+relu x2 -> l2norm gram -> powers/fusion ->
// global-max normalize -> 1x1 conv + BN(train) x2 -> sigmoid -> crop mean
// Outputs: [normal_scores(128*32), a_v(640*32*32), a_t, a_fused]
//
// R14: conv time was invariant (~125-140us) across occupancy 16-47%,
// coalescing, and weight-residency changes, with all pipes <=12% -- the
// limiter is the phase skeleton itself: hipcc emits s_waitcnt vmcnt(0)
// before every s_barrier, so each of ~14080 {stage->barrier->MFMA} phases
// carries a full memory round-trip serially per block. R9's VGPR=104
// (not ~170) also shows the compiler rematerialized the B loads, defeating
// that experiment. Fix: barrier-free, LDS-free conv. Each wave owns
// (4-batch group, tm half, K-part): A-fragments built in registers from
// its own global loads (lanes of equal m read 128B contiguous; L1 absorbs
// 3x tap overlap), B-fragments lane-linear from packed weights (proven
// layout), 18 MFMA/K-step, fp32 partials via atomicAdd. No __syncthreads,
// no __shared__ -> no forced vmcnt drains; 2560 independent wave-tasks.
// MFMA layouts (m89-verified): A[m=lane&15][k=quad*8+j],
// B[n=lane&15][k=quad*8+j], D[row=quad*4+reg][col=lane&15].
// ---------------------------------------------------------------------------

typedef __attribute__((ext_vector_type(8))) short short8;
typedef __attribute__((ext_vector_type(4))) float f32x4;

__device__ __forceinline__ unsigned short f2bf(float f) {
    __hip_bfloat16 h = __float2bfloat16(f);
    return *reinterpret_cast<unsigned short*>(&h);
}
__device__ __forceinline__ float bf2f(unsigned short u) {
    return __uint_as_float(((unsigned int)u) << 16);
}
__device__ __forceinline__ short8 glb_frag(const unsigned short* p) {
    union { uint4 u; short8 s; } r;
    r.u = *reinterpret_cast<const uint4*>(p);
    return r.s;
}

// Pack w (32, Cin, 3) fp32 -> B-fragment blocks, bf16 hi/lo, lane-linear.
// Per (slice s, tap k): 2048 ushorts = [tn][hi 512 | lo 512], within each
// 512 the order is [(quad*16+m)*8 + j] (lane L = quad*16+m reads its 8
// ushorts at L*8). Also zeroes scal and conv accumulators fv/ft.
__global__ __launch_bounds__(256) void pack_kernel(
    const float* __restrict__ wv, const float* __restrict__ wt,
    unsigned short* __restrict__ wvpk, unsigned short* __restrict__ wtpk,
    float* __restrict__ scal, float* __restrict__ fv, float* __restrict__ ft) {
    int gid = blockIdx.x * 256 + threadIdx.x;
    if (gid < 16) scal[gid] = 0.f;
    for (int i = gid; i < 655360; i += 270336) {
        fv[i] = 0.f;
        ft[i] = 0.f;
    }
    const int NV = 196608, NT = 73728;   // 32*2048*3, 32*768*3
    if (gid < NV) {
        int o = gid / 6144, rem = gid % 6144;
        int c = rem / 3, k = rem % 3;
        int s = c >> 5, cp = c & 31;
        int tn = o >> 4, m = o & 15, quad = cp >> 3, j = cp & 7;
        float f = wv[gid];
        unsigned short h = f2bf(f);
        unsigned short l = f2bf(f - bf2f(h));
        int base = (s * 3 + k) * 2048 + tn * 1024 + ((quad << 4) + m) * 8 + j;
        wvpk[base] = h;
        wvpk[base + 512] = l;
    } else if (gid < NV + NT) {
        int g = gid - NV;
        int o = g / 2304, rem = g % 2304;
        int c = rem / 3, k = rem % 3;
        int s = c >> 5, cp = c & 31;
        int tn = o >> 4, m = o & 15, quad = cp >> 3, j = cp & 7;
        float f = wt[g];
        unsigned short h = f2bf(f);
        unsigned short l = f2bf(f - bf2f(h));
        int base = (s * 3 + k) * 2048 + tn * 1024 + ((quad << 4) + m) * 8 + j;
        wtpk[base] = h;
        wtpk[base + 512] = l;
    }
}

// One conv array (visual or text) for batches [b0,b0+4), K-slices [s0,s1).
// Pure register dataflow, no LDS, no barriers. Per slice: 12 B-fragments
// (3 taps x 2 tn x hi/lo, lane-linear) then per batch g: 6 A float4 loads
// (3 tap rows x 8ch), convert to hi/lo bf16, 18 MFMAs. Out-of-range tap
// rows (t=-1, t=32) handled by clamp+zero-mask. Partials atomicAdd'ed
// (bias applied in s2; fv/ft zeroed by pack).
__device__ __forceinline__ void conv_part(
    const float* __restrict__ xb0, int Cin, int s0, int s1,
    const unsigned short* __restrict__ wpk, float* __restrict__ yout,
    int tm, int lane, int m, int quad,
    const int* roff, const float* msk) {
    f32x4 acc[4][2];
#pragma unroll
    for (int g = 0; g < 4; ++g)
#pragma unroll
        for (int tn = 0; tn < 2; ++tn)
            acc[g][tn] = (f32x4){0.f, 0.f, 0.f, 0.f};

    for (int s = s0; s < s1; ++s) {
        int c0 = s << 5;
        // B fragments for this slice: reused across 4 batches.
        short8 Bh[2][3], Bl[2][3];
        const unsigned short* wb = wpk + (size_t)s * 6144 + (lane << 3);
#pragma unroll
        for (int k = 0; k < 3; ++k)
#pragma unroll
            for (int tn = 0; tn < 2; ++tn) {
                Bh[tn][k] = glb_frag(wb + (k << 11) + (tn << 10));
                Bl[tn][k] = glb_frag(wb + (k << 11) + (tn << 10) + 512);
            }
#pragma unroll
        for (int g = 0; g < 4; ++g) {
            const float* xg = xb0 + (size_t)g * 32 * Cin + c0 + (quad << 3);
            float4 xa[3][2];
#pragma unroll
            for (int k = 0; k < 3; ++k) {
                const float* p = xg + (size_t)roff[k] * Cin;
                xa[k][0] = *reinterpret_cast<const float4*>(p);
                xa[k][1] = *reinterpret_cast<const float4*>(p + 4);
            }
#pragma unroll
            for (int k = 0; k < 3; ++k) {
                float f0 = xa[k][0].x * msk[k], f1 = xa[k][0].y * msk[k];
                float f2 = xa[k][0].z * msk[k], f3 = xa[k][0].w * msk[k];
                float f4 = xa[k][1].x * msk[k], f5 = xa[k][1].y * msk[k];
                float f6 = xa[k][1].z * msk[k], f7 = xa[k][1].w * msk[k];
                union { unsigned short u[8]; short8 s; } Ah, Al;
                unsigned short h;
                h = f2bf(f0); Ah.u[0] = h; Al.u[0] = f2bf(f0 - bf2f(h));
                h = f2bf(f1); Ah.u[1] = h; Al.u[1] = f2bf(f1 - bf2f(h));
                h = f2bf(f2); Ah.u[2] = h; Al.u[2] = f2bf(f2 - bf2f(h));
                h = f2bf(f3); Ah.u[3] = h; Al.u[3] = f2bf(f3 - bf2f(h));
                h = f2bf(f4); Ah.u[4] = h; Al.u[4] = f2bf(f4 - bf2f(h));
                h = f2bf(f5); Ah.u[5] = h; Al.u[5] = f2bf(f5 - bf2f(h));
                h = f2bf(f6); Ah.u[6] = h; Al.u[6] = f2bf(f6 - bf2f(h));
                h = f2bf(f7); Ah.u[7] = h; Al.u[7] = f2bf(f7 - bf2f(h));
#pragma unroll
                for (int tn = 0; tn < 2; ++tn) {
                    acc[g][tn] = __builtin_amdgcn_mfma_f32_16x16x32_bf16(
                        Ah.s, Bh[tn][k], acc[g][tn], 0, 0, 0);
                    acc[g][tn] = __builtin_amdgcn_mfma_f32_16x16x32_bf16(
                        Ah.s, Bl[tn][k], acc[g][tn], 0, 0, 0);
                    acc[g][tn] = __builtin_amdgcn_mfma_f32_16x16x32_bf16(
                        Al.s, Bh[tn][k], acc[g][tn], 0, 0, 0);
                }
            }
        }
    }
#pragma unroll
    for (int g = 0; g < 4; ++g)
#pragma unroll
        for (int tn = 0; tn < 2; ++tn)
#pragma unroll
            for (int r = 0; r < 4; ++r) {
                int trow = (tm << 4) + (quad << 2) + r;
                atomicAdd(&yout[g * 1024 + trow * 32 + (tn << 4) + m],
                          acc[g][tn][r]);
            }
}

// 640 blocks x 256 threads; wave-task = (batch-group of 4, tm half, kpart).
// 2560 tasks = 160 groups x 2 tm x 8 kparts. No __shared__, no barriers.
__global__ __launch_bounds__(256, 2) void conv_mfma_kernel(
    const float* __restrict__ xv, const unsigned short* __restrict__ wvpk,
    const float* __restrict__ xt, const unsigned short* __restrict__ wtpk,
    float* __restrict__ yv, float* __restrict__ yt) {
    int tid = threadIdx.x;
    int w = tid >> 6, lane = tid & 63;
    int t = blockIdx.x * 4 + w;          // 0..2559
    int group = t >> 4, rem = t & 15;
    int tm = rem >> 3, kpart = rem & 7;
    int b0 = group << 2;
    int m = lane & 15, quad = lane >> 4;

    // tap-row clamp + zero masks (depend only on m, tm)
    int roff[3];
    float msk[3];
#pragma unroll
    for (int k = 0; k < 3; ++k) {
        int r = (tm << 4) + m + k - 1;
        msk[k] = (r >= 0 && r < 32) ? 1.f : 0.f;
        roff[k] = r < 0 ? 0 : (r > 31 ? 31 : r);
    }

    // visual: 64 slices -> 8 per kpart
    conv_part(xv + (size_t)b0 * 65536, 2048, kpart << 3, (kpart << 3) + 8,
              wvpk, yv + (size_t)b0 * 1024, tm, lane, m, quad, roff, msk);
    // text: 24 slices -> 3 per kpart
    conv_part(xt + (size_t)b0 * 24576, 768, kpart * 3, kpart * 3 + 3,
              wtpk, yt + (size_t)b0 * 1024, tm, lane, m, quad, roff, msk);
}

// Per-b: bias+relu, l2norm rows, gram + relu, powers + fusion, global max.
__global__ __launch_bounds__(256) void s2_kernel(
    const float* __restrict__ fvp, const float* __restrict__ ftp,
    const float* __restrict__ bv, const float* __restrict__ bt,
    const float* __restrict__ fuse, float* __restrict__ out_av,
    float* __restrict__ out_at, float* __restrict__ out_af,
    unsigned int* __restrict__ maxslot) {
    int b = blockIdx.x, tid = threadIdx.x;
    __shared__ float Fv[32][33], Ft[32][33], inv[64], wmax[4];
#pragma unroll
    for (int e = 0; e < 4; ++e) {
        int idx = tid + 256 * e;
        int i = idx >> 5, j = idx & 31;
        Fv[i][j] = fmaxf(fvp[b * 1024 + idx] + bv[j], 0.f);
        Ft[i][j] = fmaxf(ftp[b * 1024 + idx] + bt[j], 0.f);
    }
    __syncthreads();
    {
        int row = tid >> 3, cg = (tid & 7) * 4;
        float sv = 0.f, st = 0.f;
#pragma unroll
        for (int q = 0; q < 4; ++q) {
            float v = Fv[row][cg + q]; sv = fmaf(v, v, sv);
            float u = Ft[row][cg + q]; st = fmaf(u, u, st);
        }
        sv += __shfl_xor(sv, 1); sv += __shfl_xor(sv, 2); sv += __shfl_xor(sv, 4);
        st += __shfl_xor(st, 1); st += __shfl_xor(st, 2); st += __shfl_xor(st, 4);
        if ((tid & 7) == 0) {
            inv[row]      = rsqrtf(fmaxf(sv, 1e-24f));
            inv[32 + row] = rsqrtf(fmaxf(st, 1e-24f));
        }
    }
    __syncthreads();
    float fa[16];
#pragma unroll
    for (int q = 0; q < 16; ++q) fa[q] = fuse[q];
    float lmax = 0.f;
#pragma unroll
    for (int e = 0; e < 4; ++e) {
        int idx = tid + 256 * e;
        int i = idx >> 5, j = idx & 31;
        float dv = 0.f, dt_ = 0.f;
        for (int c = 0; c < 32; ++c) {
            dv  = fmaf(Fv[i][c], Fv[j][c], dv);
            dt_ = fmaf(Ft[i][c], Ft[j][c], dt_);
        }
        float av = fmaxf(dv  * inv[i] * inv[j], 0.f);
        float at = fmaxf(dt_ * inv[32 + i] * inv[32 + j], 0.f);
        out_av[b * 1024 + idx] = av;
        out_at[b * 1024 + idx] = at;
        float pv0 = (i == j) ? 1.f : 0.f;
        float pv1 = av, pv2 = av * av, pv3 = pv2 * av;
        float pt1 = at, pt2 = at * at, pt3 = pt2 * at;
        float af = 0.f;
        af += (fa[0] * pv0 + fa[4] * pv1 + fa[8]  * pv2 + fa[12] * pv3) * pv0;
        af += (fa[1] * pv0 + fa[5] * pv1 + fa[9]  * pv2 + fa[13] * pv3) * pt1;
        af += (fa[2] * pv0 + fa[6] * pv1 + fa[10] * pv2 + fa[14] * pv3) * pt2;
        af += (fa[3] * pv0 + fa[7] * pv1 + fa[11] * pv2 + fa[15] * pv3) * pt3;
        float r = fmaxf(af, 0.f);
        out_af[b * 1024 + idx] = r;   // pre-normalization; scaled in s3
        lmax = fmaxf(lmax, r);
    }
    for (int off = 1; off < 64; off <<= 1)
        lmax = fmaxf(lmax, __shfl_xor(lmax, off));
    if ((tid & 63) == 0) wmax[tid >> 6] = lmax;
    __syncthreads();
    if (tid == 0) {
        float mx = fmaxf(fmaxf(wmax[0], wmax[1]), fmaxf(wmax[2], wmax[3]));
        atomicMax(maxslot, __float_as_uint(mx));  // valid: all values >= 0
    }
}

// Scale a_fused by 1/(max+0.01) in place; x1 = w1 @ x + b1; BN1 partial sums.
__global__ __launch_bounds__(256) void s3_kernel(
    float* __restrict__ af, const float* __restrict__ w1,
    const float* __restrict__ b1, float* __restrict__ x1,
    float* __restrict__ scal) {
    int b = blockIdx.x, tid = threadIdx.x;
    __shared__ float A[32][33];
    float inv = 1.0f / (__uint_as_float(((const unsigned int*)scal)[0]) + 0.01f);
#pragma unroll
    for (int e = 0; e < 4; ++e) {
        int idx = tid + 256 * e;
        float v = af[b * 1024 + idx] * inv;
        af[b * 1024 + idx] = v;      // final a_fused output
        A[idx >> 5][idx & 31] = v;
    }
    __syncthreads();
    if (tid < 64) {
        int o = tid >> 5, l = tid & 31;
        float s = b1[o];
        for (int c = 0; c < 32; ++c) s = fmaf(w1[o * 32 + c], A[l][c], s);
        x1[(size_t)(b * 2 + o) * 32 + l] = s;
        float s1 = s, s2 = s * s;
        for (int off = 1; off < 32; off <<= 1) {
            s1 += __shfl_xor(s1, off);
            s2 += __shfl_xor(s2, off);
        }
        if (l == 0) {
            atomicAdd(&scal[1 + o], s1);
            atomicAdd(&scal[3 + o], s2);
        }
    }
}

// BN1 finalize -> relu -> x2 = w2@h1 + b2; BN2 partial sums.
__global__ __launch_bounds__(256) void s4_kernel(
    const float* __restrict__ x1, const float* __restrict__ g1,
    const float* __restrict__ be1, const float* __restrict__ w2,
    const float* __restrict__ b2, float* __restrict__ x2,
    float* __restrict__ scal) {
    int idx = blockIdx.x * 256 + threadIdx.x;   // 20480 = 640*32
    const float N = 20480.f;
    float mu0 = scal[1] / N, mu1 = scal[2] / N;
    float va0 = scal[3] / N - mu0 * mu0, va1 = scal[4] / N - mu1 * mu1;
    float rs0 = rsqrtf(va0 + 1e-5f), rs1 = rsqrtf(va1 + 1e-5f);
    int b = idx >> 5, l = idx & 31;
    float h0 = fmaxf((x1[(size_t)(b * 2 + 0) * 32 + l] - mu0) * rs0 * g1[0] + be1[0], 0.f);
    float h1 = fmaxf((x1[(size_t)(b * 2 + 1) * 32 + l] - mu1) * rs1 * g1[1] + be1[1], 0.f);
    float v = w2[0] * h0 + w2[1] * h1 + b2[0];
    x2[idx] = v;
    float s1 = v, s2 = v * v;
    for (int off = 1; off < 64; off <<= 1) {
        s1 += __shfl_xor(s1, off);
        s2 += __shfl_xor(s2, off);
    }
    __shared__ float ps[4][2];
    int lane = threadIdx.x & 63, w = threadIdx.x >> 6;
    if (lane == 0) { ps[w][0] = s1; ps[w][1] = s2; }
    __syncthreads();
    if (threadIdx.x == 0) {
        atomicAdd(&scal[5], ps[0][0] + ps[1][0] + ps[2][0] + ps[3][0]);
        atomicAdd(&scal[6], ps[0][1] + ps[1][1] + ps[2][1] + ps[3][1]);
    }
}

// BN2 -> relu -> sigmoid(w3*h2+b3) -> mean over 5 crops.
__global__ __launch_bounds__(256) void s5_kernel(
    const float* __restrict__ x2, const float* __restrict__ g2,
    const float* __restrict__ be2, const float* __restrict__ w3,
    const float* __restrict__ b3, float* __restrict__ ns,
    const float* __restrict__ scal) {
    int idx = blockIdx.x * 256 + threadIdx.x;   // 4096 = 128*32
    const float N = 20480.f;
    float mu = scal[5] / N;
    float var = scal[6] / N - mu * mu;
    float rs = rsqrtf(var + 1e-5f);
    int bb = idx >> 5, t = idx & 31;
    float s = 0.f;
#pragma unroll
    for (int crop = 0; crop < 5; ++crop) {
        int b = bb * 5 + crop;
        float h = fmaxf((x2[b * 32 + t] - mu) * rs * g2[0] + be2[0], 0.f);
        float z = w3[0] * h + b3[0];
        s += 1.f / (1.f + expf(-z));
    }
    ns[idx] = s * 0.2f;
}

extern "C" void kernel_launch(void* const* d_in, const int* in_sizes, int n_in,
                              void* d_out, int out_size, void* d_ws, size_t ws_size,
                              hipStream_t stream) {
    const float* v_feat = (const float*)d_in[0];
    const float* t_feat = (const float*)d_in[1];
    const float* wv  = (const float*)d_in[2];
    const float* bv  = (const float*)d_in[3];
    const float* wt  = (const float*)d_in[4];
    const float* bt  = (const float*)d_in[5];
    const float* fuse= (const float*)d_in[6];
    const float* w1  = (const float*)d_in[7];
    const float* b1  = (const float*)d_in[8];
    const float* g1  = (const float*)d_in[9];
    const float* be1 = (const float*)d_in[10];
    const float* w2  = (const float*)d_in[11];
    const float* b2  = (const float*)d_in[12];
    const float* g2  = (const float*)d_in[13];
    const float* be2 = (const float*)d_in[14];
    const float* w3  = (const float*)d_in[15];
    const float* b3  = (const float*)d_in[16];

    float* ws   = (float*)d_ws;
    float* scal = ws;                       // [0]=max(uint), [1..4]=BN1, [5..6]=BN2
    unsigned short* wvpk = (unsigned short*)(ws + 16);          // 393216 ushorts
    unsigned short* wtpk = (unsigned short*)(ws + 16 + 196608); // 147456 ushorts
    float* fv   = ws + 16 + 196608 + 73728; // 655360
    float* ft   = fv + 655360;              // 655360
    float* x1   = ft + 655360;              // 40960
    float* x2   = x1 + 40960;               // 20480

    float* out_ns = (float*)d_out;          // 4096
    float* out_av = out_ns + 4096;          // 655360
    float* out_at = out_av + 655360;        // 655360
    float* out_af = out_at + 655360;        // 655360

    pack_kernel<<<1056, 256, 0, stream>>>(wv, wt, wvpk, wtpk, scal, fv, ft);
    conv_mfma_kernel<<<640, 256, 0, stream>>>(v_feat, wvpk, t_feat, wtpk, fv, ft);
    s2_kernel<<<640, 256, 0, stream>>>(fv, ft, bv, bt, fuse, out_av, out_at,
                                       out_af, (unsigned int*)scal);
    s3_kernel<<<640, 256, 0, stream>>>(out_af, w1, b1, x1, scal);
    s4_kernel<<<80, 256, 0, stream>>>(x1, g1, be1, w2, b2, x2, scal);
    s5_kernel<<<16, 256, 0, stream>>>(x2, g2, be2, w3, b3, out_ns, scal);
}

// Round 12
// 391.545 us; speedup vs baseline: 1.0944x; 1.0944x over previous
//
#include <hip/hip_runtime.h>
#include <hip/hip_bf16.h>
#include <math.h>

// ---------------------------------------------------------------------------
// GraphClassifiction: conv1d(k=3)+relu x2 -> l2norm gram -> powers/fusion ->
// global-max normalize -> 1x1 conv + BN(train) x2 -> sigmoid -> crop mean
// Outputs: [normal_scores(128*32), a_v(640*32*32), a_t, a_fused]
//
// R17 == R15 resubmitted (R10/R11 benches were GPU-acquisition timeouts;
// R15 never ran). Conv is the measured-best variant (R2 bench, 125us:
// lane-linear packed B, reg prefetch, XROW=136, grid 2560, lb(256,4)).
// Ten rounds showed conv pinned at ~1TB/s effective across ALL structures
// (compiler allocates few load-dest VGPRs -> few loads in flight); further
// source-level conv rewrites are not productive. This round attacks the
// ~235us non-conv residue instead: s3 is ELIMINATED via linearity --
// x1 = inv*(w1@af_unscaled) + b1, and BN1 stats are closed-form in
// S1,S2 of u1=w1@af_unscaled and inv (b1 cancels in the normalized
// form). s2 computes u1 + sums (af tile already in LDS); new s4 (640
// blocks) scales out_af in place and runs BN1->x2->BN2-sums. 5 launches.
// MFMA layouts (m89-verified): A[m=lane&15][k=quad*8+j],
// B[n=lane&15][k=quad*8+j], D[row=quad*4+reg][col=lane&15].
// ---------------------------------------------------------------------------

typedef __attribute__((ext_vector_type(8))) short short8;
typedef __attribute__((ext_vector_type(4))) float f32x4;

#define XROW 136   // ushorts per LDS row: 128 data + 8 pad; 272B rows, 16B-aligned

__device__ __forceinline__ unsigned short f2bf(float f) {
    __hip_bfloat16 h = __float2bfloat16(f);
    return *reinterpret_cast<unsigned short*>(&h);
}
__device__ __forceinline__ float bf2f(unsigned short u) {
    return __uint_as_float(((unsigned int)u) << 16);
}
__device__ __forceinline__ short8 lds_frag(const unsigned short* p) {
    union { uint4 u; short8 s; } r;
    r.u = *reinterpret_cast<const uint4*>(p);   // ds_read_b128
    return r.s;
}
__device__ __forceinline__ short8 glb_frag(const unsigned short* p) {
    union { uint4 u; short8 s; } r;
    r.u = *reinterpret_cast<const uint4*>(p);
    return r.s;
}

// Pack w (32, Cin, 3) fp32 -> B-fragment blocks, bf16 hi/lo, lane-linear.
// Per (slice s, tap k): 2048 ushorts = [tn][hi 512 | lo 512], within each
// 512 the order is [(quad*16+m)*8 + j] (lane L = quad*16+m reads its 8
// ushorts at L*8). Also zeroes scal and conv accumulators fv/ft.
__global__ __launch_bounds__(256) void pack_kernel(
    const float* __restrict__ wv, const float* __restrict__ wt,
    unsigned short* __restrict__ wvpk, unsigned short* __restrict__ wtpk,
    float* __restrict__ scal, float* __restrict__ fv, float* __restrict__ ft) {
    int gid = blockIdx.x * 256 + threadIdx.x;
    if (gid < 16) scal[gid] = 0.f;
    for (int i = gid; i < 655360; i += 270336) {
        fv[i] = 0.f;
        ft[i] = 0.f;
    }
    const int NV = 196608, NT = 73728;   // 32*2048*3, 32*768*3
    if (gid < NV) {
        int o = gid / 6144, rem = gid % 6144;
        int c = rem / 3, k = rem % 3;
        int s = c >> 5, cp = c & 31;
        int tn = o >> 4, m = o & 15, quad = cp >> 3, j = cp & 7;
        float f = wv[gid];
        unsigned short h = f2bf(f);
        unsigned short l = f2bf(f - bf2f(h));
        int base = (s * 3 + k) * 2048 + tn * 1024 + ((quad << 4) + m) * 8 + j;
        wvpk[base] = h;
        wvpk[base + 512] = l;
    } else if (gid < NV + NT) {
        int g = gid - NV;
        int o = g / 2304, rem = g % 2304;
        int c = rem / 3, k = rem % 3;
        int s = c >> 5, cp = c & 31;
        int tn = o >> 4, m = o & 15, quad = cp >> 3, j = cp & 7;
        float f = wt[g];
        unsigned short h = f2bf(f);
        unsigned short l = f2bf(f - bf2f(h));
        int base = (s * 3 + k) * 2048 + tn * 1024 + ((quad << 4) + m) * 8 + j;
        wtpk[base] = h;
        wtpk[base + 512] = l;
    }
}

// One conv (visual or text) for one batch b, channel-chunk range [ch0,ch1).
// 4 waves: wave -> (tm,tn) 16x16 output tile. K streamed in 128-ch chunks
// staged to LDS as hi/lo bf16 tiles [row 0..33][c], row = t+1, rows 0/33
// zero (conv pad). Tap k = A-read at row+k. acc0=hh, acc1=hl+lh.
// Next chunk's activations prefetched to regs during MFMA.
// Partial result atomicAdd'ed to yout (bias added in s2).
__device__ __forceinline__ void conv_phase(
    const float* __restrict__ xb, int Cin,
    const unsigned short* __restrict__ wpk,
    unsigned short* hiT, unsigned short* loT,
    float* __restrict__ yout, int tid, int wave, int lane, int part) {
    int tm = wave & 1, tn = wave >> 1;
    int m = lane & 15, quad = lane >> 4;
    int c4 = tid & 31, tg = tid >> 5;
    int nchunk = Cin >> 7;
    int ch0 = (nchunk * part) >> 2;
    int ch1 = (nchunk * (part + 1)) >> 2;

    const float* xbase = xb + (c4 << 2);
    float4 xq0, xq1, xq2, xq3;
    // prologue prefetch (pure-register; issues before the entry barrier)
    {
        const float* p = xbase + (size_t)(ch0 << 7);
        xq0 = *reinterpret_cast<const float4*>(p + (size_t)tg * Cin);
        xq1 = *reinterpret_cast<const float4*>(p + (size_t)(tg + 8) * Cin);
        xq2 = *reinterpret_cast<const float4*>(p + (size_t)(tg + 16) * Cin);
        xq3 = *reinterpret_cast<const float4*>(p + (size_t)(tg + 24) * Cin);
    }
    __syncthreads();   // previous phase's LDS readers done
    if (tid < XROW) {
        hiT[tid] = 0; hiT[33 * XROW + tid] = 0;
        loT[tid] = 0; loT[33 * XROW + tid] = 0;
    }
    f32x4 acc0 = {0.f, 0.f, 0.f, 0.f};
    f32x4 acc1 = {0.f, 0.f, 0.f, 0.f};

    auto stage = [&](const float4& xq, int t) {
        unsigned short h0 = f2bf(xq.x), h1 = f2bf(xq.y);
        unsigned short h2 = f2bf(xq.z), h3 = f2bf(xq.w);
        unsigned short l0 = f2bf(xq.x - bf2f(h0));
        unsigned short l1 = f2bf(xq.y - bf2f(h1));
        unsigned short l2 = f2bf(xq.z - bf2f(h2));
        unsigned short l3 = f2bf(xq.w - bf2f(h3));
        int widx = (t + 1) * XROW + (c4 << 2);
        *reinterpret_cast<uint2*>(hiT + widx) =
            make_uint2(h0 | ((unsigned int)h1 << 16), h2 | ((unsigned int)h3 << 16));
        *reinterpret_cast<uint2*>(loT + widx) =
            make_uint2(l0 | ((unsigned int)l1 << 16), l2 | ((unsigned int)l3 << 16));
    };

    for (int ch = ch0; ch < ch1; ++ch) {
        __syncthreads();   // prev chunk's readers done (also pad-zero vis)
        stage(xq0, tg);
        stage(xq1, tg + 8);
        stage(xq2, tg + 16);
        stage(xq3, tg + 24);
        __syncthreads();   // staging visible
        if (ch + 1 < ch1) {   // prefetch next chunk; latency hides under MFMA
            const float* p = xbase + (size_t)((ch + 1) << 7);
            xq0 = *reinterpret_cast<const float4*>(p + (size_t)tg * Cin);
            xq1 = *reinterpret_cast<const float4*>(p + (size_t)(tg + 8) * Cin);
            xq2 = *reinterpret_cast<const float4*>(p + (size_t)(tg + 16) * Cin);
            xq3 = *reinterpret_cast<const float4*>(p + (size_t)(tg + 24) * Cin);
        }
        int sbase = ch << 2;
        int arow0 = (tm << 4) + m;
        int bofs = (tn << 10) + (lane << 3);
#pragma unroll
        for (int sl = 0; sl < 4; ++sl) {
            int acol = (sl << 5) + (quad << 3);
            const unsigned short* bbase = wpk + (size_t)(sbase + sl) * 6144 + bofs;
#pragma unroll
            for (int k = 0; k < 3; ++k) {
                short8 Ah = lds_frag(hiT + (arow0 + k) * XROW + acol);
                short8 Al = lds_frag(loT + (arow0 + k) * XROW + acol);
                short8 Bh = glb_frag(bbase + (k << 11));
                short8 Bl = glb_frag(bbase + (k << 11) + 512);
                acc0 = __builtin_amdgcn_mfma_f32_16x16x32_bf16(Ah, Bh, acc0, 0, 0, 0);
                acc1 = __builtin_amdgcn_mfma_f32_16x16x32_bf16(Ah, Bl, acc1, 0, 0, 0);
                acc1 = __builtin_amdgcn_mfma_f32_16x16x32_bf16(Al, Bh, acc1, 0, 0, 0);
            }
        }
    }
    int ocol = (tn << 4) + m;
#pragma unroll
    for (int r = 0; r < 4; ++r) {
        int t = (tm << 4) + (quad << 2) + r;
        atomicAdd(&yout[t * 32 + ocol], acc0[r] + acc1[r]);
    }
}

__global__ __launch_bounds__(256, 4) void conv_mfma_kernel(
    const float* __restrict__ xv, const unsigned short* __restrict__ wvpk,
    const float* __restrict__ xt, const unsigned short* __restrict__ wtpk,
    float* __restrict__ yv, float* __restrict__ yt) {
    __shared__ unsigned short hiT[34 * XROW], loT[34 * XROW];
    int bx = blockIdx.x;
    int b = bx >> 2, part = bx & 3;
    int tid = threadIdx.x;
    int wave = tid >> 6, lane = tid & 63;
    conv_phase(xv + (size_t)b * 32 * 2048, 2048, wvpk, hiT, loT,
               yv + (size_t)b * 1024, tid, wave, lane, part);
    conv_phase(xt + (size_t)b * 32 * 768, 768, wtpk, hiT, loT,
               yt + (size_t)b * 1024, tid, wave, lane, part);
}

// Per-b: bias+relu, l2norm rows, gram + relu, powers + fusion, global max,
// AND u1 = w1 @ af_unscaled with partial sums S1,S2 -> scal[1..4]
// (linearity: x1 = inv*u1 + b1, so BN1 stats are closed-form later).
__global__ __launch_bounds__(256) void s2_kernel(
    const float* __restrict__ fvp, const float* __restrict__ ftp,
    const float* __restrict__ bv, const float* __restrict__ bt,
    const float* __restrict__ fuse, const float* __restrict__ w1,
    float* __restrict__ out_av, float* __restrict__ out_at,
    float* __restrict__ out_af, float* __restrict__ u1ws,
    float* __restrict__ scal) {
    int b = blockIdx.x, tid = threadIdx.x;
    __shared__ float Fv[32][33], Ft[32][33], Af[32][33], inv[64], wmax[4];
#pragma unroll
    for (int e = 0; e < 4; ++e) {
        int idx = tid + 256 * e;
        int i = idx >> 5, j = idx & 31;
        Fv[i][j] = fmaxf(fvp[b * 1024 + idx] + bv[j], 0.f);
        Ft[i][j] = fmaxf(ftp[b * 1024 + idx] + bt[j], 0.f);
    }
    __syncthreads();
    {
        int row = tid >> 3, cg = (tid & 7) * 4;
        float sv = 0.f, st = 0.f;
#pragma unroll
        for (int q = 0; q < 4; ++q) {
            float v = Fv[row][cg + q]; sv = fmaf(v, v, sv);
            float u = Ft[row][cg + q]; st = fmaf(u, u, st);
        }
        sv += __shfl_xor(sv, 1); sv += __shfl_xor(sv, 2); sv += __shfl_xor(sv, 4);
        st += __shfl_xor(st, 1); st += __shfl_xor(st, 2); st += __shfl_xor(st, 4);
        if ((tid & 7) == 0) {
            inv[row]      = rsqrtf(fmaxf(sv, 1e-24f));
            inv[32 + row] = rsqrtf(fmaxf(st, 1e-24f));
        }
    }
    __syncthreads();
    float fa[16];
#pragma unroll
    for (int q = 0; q < 16; ++q) fa[q] = fuse[q];
    float lmax = 0.f;
#pragma unroll
    for (int e = 0; e < 4; ++e) {
        int idx = tid + 256 * e;
        int i = idx >> 5, j = idx & 31;
        float dv = 0.f, dt_ = 0.f;
        for (int c = 0; c < 32; ++c) {
            dv  = fmaf(Fv[i][c], Fv[j][c], dv);
            dt_ = fmaf(Ft[i][c], Ft[j][c], dt_);
        }
        float av = fmaxf(dv  * inv[i] * inv[j], 0.f);
        float at = fmaxf(dt_ * inv[32 + i] * inv[32 + j], 0.f);
        out_av[b * 1024 + idx] = av;
        out_at[b * 1024 + idx] = at;
        float pv0 = (i == j) ? 1.f : 0.f;
        float pv1 = av, pv2 = av * av, pv3 = pv2 * av;
        float pt1 = at, pt2 = at * at, pt3 = pt2 * at;
        float af = 0.f;
        af += (fa[0] * pv0 + fa[4] * pv1 + fa[8]  * pv2 + fa[12] * pv3) * pv0;
        af += (fa[1] * pv0 + fa[5] * pv1 + fa[9]  * pv2 + fa[13] * pv3) * pt1;
        af += (fa[2] * pv0 + fa[6] * pv1 + fa[10] * pv2 + fa[14] * pv3) * pt2;
        af += (fa[3] * pv0 + fa[7] * pv1 + fa[11] * pv2 + fa[15] * pv3) * pt3;
        float r = fmaxf(af, 0.f);
        out_af[b * 1024 + idx] = r;   // pre-normalization; scaled in s4
        Af[i][j] = r;
        lmax = fmaxf(lmax, r);
    }
    for (int off = 1; off < 64; off <<= 1)
        lmax = fmaxf(lmax, __shfl_xor(lmax, off));
    if ((tid & 63) == 0) wmax[tid >> 6] = lmax;
    __syncthreads();   // Af complete + wmax visible
    if (tid == 0) {
        float mx = fmaxf(fmaxf(wmax[0], wmax[1]), fmaxf(wmax[2], wmax[3]));
        atomicMax((unsigned int*)scal, __float_as_uint(mx));  // values >= 0
    }
    // u1[b,o,l] = sum_c w1[o,c] * af_unscaled[b,l,c]; partial sums -> scal
    if (tid < 64) {
        int o = tid >> 5, l = tid & 31;
        float s = 0.f;
        for (int c = 0; c < 32; ++c) s = fmaf(w1[o * 32 + c], Af[l][c], s);
        u1ws[(size_t)(b * 2 + o) * 32 + l] = s;
        float s1 = s, s2 = s * s;
        for (int off = 1; off < 32; off <<= 1) {
            s1 += __shfl_xor(s1, off);
            s2 += __shfl_xor(s2, off);
        }
        if (l == 0) {
            atomicAdd(&scal[1 + o], s1);
            atomicAdd(&scal[3 + o], s2);
        }
    }
}

// Scale a_fused in place by inv=1/(max+0.01); BN1 (closed-form from u1
// sums: x1 = inv*u1 + b1 -> x1-mu = inv*(u1-m), var = inv^2*var_u; b1
// cancels) -> relu -> x2 = w2@h1 + b2; BN2 partial sums -> scal[5,6].
__global__ __launch_bounds__(256) void s4_kernel(
    float* __restrict__ af, const float* __restrict__ u1,
    const float* __restrict__ g1, const float* __restrict__ be1,
    const float* __restrict__ w2, const float* __restrict__ b2,
    float* __restrict__ x2, const float* __restrict__ scal) {
    int b = blockIdx.x, tid = threadIdx.x;
    float invs = 1.0f / (__uint_as_float(((const unsigned int*)scal)[0]) + 0.01f);
#pragma unroll
    for (int e = 0; e < 4; ++e) {
        int idx = tid + 256 * e;
        af[(size_t)b * 1024 + idx] *= invs;   // final a_fused output
    }
    if (tid < 32) {
        const float N = 20480.f;
        float m0 = scal[1] / N, m1 = scal[2] / N;
        float rs0 = rsqrtf(invs * invs * (scal[3] / N - m0 * m0) + 1e-5f);
        float rs1 = rsqrtf(invs * invs * (scal[4] / N - m1 * m1) + 1e-5f);
        float u0 = u1[(size_t)(b * 2 + 0) * 32 + tid];
        float u1v = u1[(size_t)(b * 2 + 1) * 32 + tid];
        float h0 = fmaxf(invs * (u0 - m0) * rs0 * g1[0] + be1[0], 0.f);
        float h1 = fmaxf(invs * (u1v - m1) * rs1 * g1[1] + be1[1], 0.f);
        float v = w2[0] * h0 + w2[1] * h1 + b2[0];
        x2[(size_t)b * 32 + tid] = v;
        float s1 = v, s2 = v * v;
        for (int off = 1; off < 32; off <<= 1) {
            s1 += __shfl_xor(s1, off);
            s2 += __shfl_xor(s2, off);
        }
        if (tid == 0) {
            atomicAdd((float*)&scal[5], s1);
            atomicAdd((float*)&scal[6], s2);
        }
    }
}

// BN2 -> relu -> sigmoid(w3*h2+b3) -> mean over 5 crops.
__global__ __launch_bounds__(256) void s5_kernel(
    const float* __restrict__ x2, const float* __restrict__ g2,
    const float* __restrict__ be2, const float* __restrict__ w3,
    const float* __restrict__ b3, float* __restrict__ ns,
    const float* __restrict__ scal) {
    int idx = blockIdx.x * 256 + threadIdx.x;   // 4096 = 128*32
    const float N = 20480.f;
    float mu = scal[5] / N;
    float var = scal[6] / N - mu * mu;
    float rs = rsqrtf(var + 1e-5f);
    int bb = idx >> 5, t = idx & 31;
    float s = 0.f;
#pragma unroll
    for (int crop = 0; crop < 5; ++crop) {
        int b = bb * 5 + crop;
        float h = fmaxf((x2[b * 32 + t] - mu) * rs * g2[0] + be2[0], 0.f);
        float z = w3[0] * h + b3[0];
        s += 1.f / (1.f + expf(-z));
    }
    ns[idx] = s * 0.2f;
}

extern "C" void kernel_launch(void* const* d_in, const int* in_sizes, int n_in,
                              void* d_out, int out_size, void* d_ws, size_t ws_size,
                              hipStream_t stream) {
    const float* v_feat = (const float*)d_in[0];
    const float* t_feat = (const float*)d_in[1];
    const float* wv  = (const float*)d_in[2];
    const float* bv  = (const float*)d_in[3];
    const float* wt  = (const float*)d_in[4];
    const float* bt  = (const float*)d_in[5];
    const float* fuse= (const float*)d_in[6];
    const float* w1  = (const float*)d_in[7];
    const float* b1  = (const float*)d_in[8];   // cancels in closed-form BN1
    const float* g1  = (const float*)d_in[9];
    const float* be1 = (const float*)d_in[10];
    const float* w2  = (const float*)d_in[11];
    const float* b2  = (const float*)d_in[12];
    const float* g2  = (const float*)d_in[13];
    const float* be2 = (const float*)d_in[14];
    const float* w3  = (const float*)d_in[15];
    const float* b3  = (const float*)d_in[16];
    (void)b1;

    float* ws   = (float*)d_ws;
    float* scal = ws;                       // [0]=max(uint), [1..4]=u1 S1/S2, [5..6]=BN2
    unsigned short* wvpk = (unsigned short*)(ws + 16);          // 393216 ushorts
    unsigned short* wtpk = (unsigned short*)(ws + 16 + 196608); // 147456 ushorts
    float* fv   = ws + 16 + 196608 + 73728; // 655360
    float* ft   = fv + 655360;              // 655360
    float* u1   = ft + 655360;              // 40960
    float* x2   = u1 + 40960;               // 20480

    float* out_ns = (float*)d_out;          // 4096
    float* out_av = out_ns + 4096;          // 655360
    float* out_at = out_av + 655360;        // 655360
    float* out_af = out_at + 655360;        // 655360

    pack_kernel<<<1056, 256, 0, stream>>>(wv, wt, wvpk, wtpk, scal, fv, ft);
    conv_mfma_kernel<<<2560, 256, 0, stream>>>(v_feat, wvpk, t_feat, wtpk, fv, ft);
    s2_kernel<<<640, 256, 0, stream>>>(fv, ft, bv, bt, fuse, w1, out_av, out_at,
                                       out_af, u1, scal);
    s4_kernel<<<640, 256, 0, stream>>>(out_af, u1, g1, be1, w2, b2, x2, scal);
    s5_kernel<<<16, 256, 0, stream>>>(x2, g2, be2, w3, b3, out_ns, scal);
}

// Round 13
// 390.510 us; speedup vs baseline: 1.0973x; 1.0026x over previous
//
#include <hip/hip_runtime.h>
#include <hip/hip_bf16.h>
#include <math.h>

// ---------------------------------------------------------------------------
// GraphClassifiction: conv1d(k=3)+relu x2 -> l2norm gram -> powers/fusion ->
// global-max normalize -> 1x1 conv + BN(train) x2 -> sigmoid -> crop mean
// Outputs: [normal_scores(128*32), a_v(640*32*32), a_t, a_fused]
//
// R18: R12 measured conv at 124us with ~15K cy/chunk vs ~2K of work. The
// one documented, unexploited lever: __syncthreads() emits s_waitcnt
// vmcnt(0) before s_barrier (m97), so the chunk-ahead register prefetch
// added in R7 is DRAINED at every top-of-loop barrier -- each chunk pays
// full HBM latency serially. Fix (m201 technique, single variable):
// replace __syncthreads in conv_phase with raw __builtin_amdgcn_s_barrier
// + asm lgkmcnt(0) (LDS-only visibility). Prefetch loads now stay in
// flight across barriers; their wait lands at stage_row use one full
// phase later. Everything else byte-identical to R12 (passed, absmax
// 0.0039): lane-linear packed B, XROW=136, grid 2560, lb(256,4), s3
// eliminated via BN1 linearity (u1 in s2, closed-form BN1 in s4).
// MFMA layouts (m89-verified): A[m=lane&15][k=quad*8+j],
// B[n=lane&15][k=quad*8+j], D[row=quad*4+reg][col=lane&15].
// ---------------------------------------------------------------------------

typedef __attribute__((ext_vector_type(8))) short short8;
typedef __attribute__((ext_vector_type(4))) float f32x4;

#define XROW 136   // ushorts per LDS row: 128 data + 8 pad; 272B rows, 16B-aligned

__device__ __forceinline__ unsigned short f2bf(float f) {
    __hip_bfloat16 h = __float2bfloat16(f);
    return *reinterpret_cast<unsigned short*>(&h);
}
__device__ __forceinline__ float bf2f(unsigned short u) {
    return __uint_as_float(((unsigned int)u) << 16);
}
__device__ __forceinline__ short8 lds_frag(const unsigned short* p) {
    union { uint4 u; short8 s; } r;
    r.u = *reinterpret_cast<const uint4*>(p);   // ds_read_b128
    return r.s;
}
__device__ __forceinline__ short8 glb_frag(const unsigned short* p) {
    union { uint4 u; short8 s; } r;
    r.u = *reinterpret_cast<const uint4*>(p);
    return r.s;
}

// LDS-only barrier: waits ds ops (lgkmcnt) but leaves global loads in
// flight across the barrier (unlike __syncthreads' vmcnt(0) drain).
__device__ __forceinline__ void lds_barrier() {
    asm volatile("s_waitcnt lgkmcnt(0)" ::: "memory");
    __builtin_amdgcn_s_barrier();
}

// Pack w (32, Cin, 3) fp32 -> B-fragment blocks, bf16 hi/lo, lane-linear.
// Per (slice s, tap k): 2048 ushorts = [tn][hi 512 | lo 512], within each
// 512 the order is [(quad*16+m)*8 + j] (lane L = quad*16+m reads its 8
// ushorts at L*8). Also zeroes scal and conv accumulators fv/ft.
__global__ __launch_bounds__(256) void pack_kernel(
    const float* __restrict__ wv, const float* __restrict__ wt,
    unsigned short* __restrict__ wvpk, unsigned short* __restrict__ wtpk,
    float* __restrict__ scal, float* __restrict__ fv, float* __restrict__ ft) {
    int gid = blockIdx.x * 256 + threadIdx.x;
    if (gid < 16) scal[gid] = 0.f;
    for (int i = gid; i < 655360; i += 270336) {
        fv[i] = 0.f;
        ft[i] = 0.f;
    }
    const int NV = 196608, NT = 73728;   // 32*2048*3, 32*768*3
    if (gid < NV) {
        int o = gid / 6144, rem = gid % 6144;
        int c = rem / 3, k = rem % 3;
        int s = c >> 5, cp = c & 31;
        int tn = o >> 4, m = o & 15, quad = cp >> 3, j = cp & 7;
        float f = wv[gid];
        unsigned short h = f2bf(f);
        unsigned short l = f2bf(f - bf2f(h));
        int base = (s * 3 + k) * 2048 + tn * 1024 + ((quad << 4) + m) * 8 + j;
        wvpk[base] = h;
        wvpk[base + 512] = l;
    } else if (gid < NV + NT) {
        int g = gid - NV;
        int o = g / 2304, rem = g % 2304;
        int c = rem / 3, k = rem % 3;
        int s = c >> 5, cp = c & 31;
        int tn = o >> 4, m = o & 15, quad = cp >> 3, j = cp & 7;
        float f = wt[g];
        unsigned short h = f2bf(f);
        unsigned short l = f2bf(f - bf2f(h));
        int base = (s * 3 + k) * 2048 + tn * 1024 + ((quad << 4) + m) * 8 + j;
        wtpk[base] = h;
        wtpk[base + 512] = l;
    }
}

// One conv (visual or text) for one batch b, channel-chunk range [ch0,ch1).
// 4 waves: wave -> (tm,tn) 16x16 output tile. K streamed in 128-ch chunks
// staged to LDS as hi/lo bf16 tiles [row 0..33][c], row = t+1, rows 0/33
// zero (conv pad). Tap k = A-read at row+k. acc0=hh, acc1=hl+lh.
// Next chunk's activations prefetched to regs during MFMA; lds_barrier
// (lgkmcnt-only) keeps those loads in flight across barriers.
// Partial result atomicAdd'ed to yout (bias added in s2).
__device__ __forceinline__ void conv_phase(
    const float* __restrict__ xb, int Cin,
    const unsigned short* __restrict__ wpk,
    unsigned short* hiT, unsigned short* loT,
    float* __restrict__ yout, int tid, int wave, int lane, int part) {
    int tm = wave & 1, tn = wave >> 1;
    int m = lane & 15, quad = lane >> 4;
    int c4 = tid & 31, tg = tid >> 5;
    int nchunk = Cin >> 7;
    int ch0 = (nchunk * part) >> 2;
    int ch1 = (nchunk * (part + 1)) >> 2;

    const float* xbase = xb + (c4 << 2);
    float4 xq0, xq1, xq2, xq3;
    // prologue prefetch (stays in flight across the entry barrier)
    {
        const float* p = xbase + (size_t)(ch0 << 7);
        xq0 = *reinterpret_cast<const float4*>(p + (size_t)tg * Cin);
        xq1 = *reinterpret_cast<const float4*>(p + (size_t)(tg + 8) * Cin);
        xq2 = *reinterpret_cast<const float4*>(p + (size_t)(tg + 16) * Cin);
        xq3 = *reinterpret_cast<const float4*>(p + (size_t)(tg + 24) * Cin);
    }
    lds_barrier();   // previous phase's LDS readers done
    if (tid < XROW) {
        hiT[tid] = 0; hiT[33 * XROW + tid] = 0;
        loT[tid] = 0; loT[33 * XROW + tid] = 0;
    }
    f32x4 acc0 = {0.f, 0.f, 0.f, 0.f};
    f32x4 acc1 = {0.f, 0.f, 0.f, 0.f};

    auto stage = [&](const float4& xq, int t) {
        unsigned short h0 = f2bf(xq.x), h1 = f2bf(xq.y);
        unsigned short h2 = f2bf(xq.z), h3 = f2bf(xq.w);
        unsigned short l0 = f2bf(xq.x - bf2f(h0));
        unsigned short l1 = f2bf(xq.y - bf2f(h1));
        unsigned short l2 = f2bf(xq.z - bf2f(h2));
        unsigned short l3 = f2bf(xq.w - bf2f(h3));
        int widx = (t + 1) * XROW + (c4 << 2);
        *reinterpret_cast<uint2*>(hiT + widx) =
            make_uint2(h0 | ((unsigned int)h1 << 16), h2 | ((unsigned int)h3 << 16));
        *reinterpret_cast<uint2*>(loT + widx) =
            make_uint2(l0 | ((unsigned int)l1 << 16), l2 | ((unsigned int)l3 << 16));
    };

    for (int ch = ch0; ch < ch1; ++ch) {
        lds_barrier();   // prev chunk's readers done (also pad-zero vis)
        stage(xq0, tg);
        stage(xq1, tg + 8);
        stage(xq2, tg + 16);
        stage(xq3, tg + 24);
        lds_barrier();   // staging visible
        if (ch + 1 < ch1) {   // prefetch next chunk; crosses next barrier in flight
            const float* p = xbase + (size_t)((ch + 1) << 7);
            xq0 = *reinterpret_cast<const float4*>(p + (size_t)tg * Cin);
            xq1 = *reinterpret_cast<const float4*>(p + (size_t)(tg + 8) * Cin);
            xq2 = *reinterpret_cast<const float4*>(p + (size_t)(tg + 16) * Cin);
            xq3 = *reinterpret_cast<const float4*>(p + (size_t)(tg + 24) * Cin);
        }
        int sbase = ch << 2;
        int arow0 = (tm << 4) + m;
        int bofs = (tn << 10) + (lane << 3);
#pragma unroll
        for (int sl = 0; sl < 4; ++sl) {
            int acol = (sl << 5) + (quad << 3);
            const unsigned short* bbase = wpk + (size_t)(sbase + sl) * 6144 + bofs;
#pragma unroll
            for (int k = 0; k < 3; ++k) {
                short8 Ah = lds_frag(hiT + (arow0 + k) * XROW + acol);
                short8 Al = lds_frag(loT + (arow0 + k) * XROW + acol);
                short8 Bh = glb_frag(bbase + (k << 11));
                short8 Bl = glb_frag(bbase + (k << 11) + 512);
                acc0 = __builtin_amdgcn_mfma_f32_16x16x32_bf16(Ah, Bh, acc0, 0, 0, 0);
                acc1 = __builtin_amdgcn_mfma_f32_16x16x32_bf16(Ah, Bl, acc1, 0, 0, 0);
                acc1 = __builtin_amdgcn_mfma_f32_16x16x32_bf16(Al, Bh, acc1, 0, 0, 0);
            }
        }
    }
    int ocol = (tn << 4) + m;
#pragma unroll
    for (int r = 0; r < 4; ++r) {
        int t = (tm << 4) + (quad << 2) + r;
        atomicAdd(&yout[t * 32 + ocol], acc0[r] + acc1[r]);
    }
}

__global__ __launch_bounds__(256, 4) void conv_mfma_kernel(
    const float* __restrict__ xv, const unsigned short* __restrict__ wvpk,
    const float* __restrict__ xt, const unsigned short* __restrict__ wtpk,
    float* __restrict__ yv, float* __restrict__ yt) {
    __shared__ unsigned short hiT[34 * XROW], loT[34 * XROW];
    int bx = blockIdx.x;
    int b = bx >> 2, part = bx & 3;
    int tid = threadIdx.x;
    int wave = tid >> 6, lane = tid & 63;
    conv_phase(xv + (size_t)b * 32 * 2048, 2048, wvpk, hiT, loT,
               yv + (size_t)b * 1024, tid, wave, lane, part);
    conv_phase(xt + (size_t)b * 32 * 768, 768, wtpk, hiT, loT,
               yt + (size_t)b * 1024, tid, wave, lane, part);
}

// Per-b: bias+relu, l2norm rows, gram + relu, powers + fusion, global max,
// AND u1 = w1 @ af_unscaled with partial sums S1,S2 -> scal[1..4]
// (linearity: x1 = inv*u1 + b1, so BN1 stats are closed-form later).
__global__ __launch_bounds__(256) void s2_kernel(
    const float* __restrict__ fvp, const float* __restrict__ ftp,
    const float* __restrict__ bv, const float* __restrict__ bt,
    const float* __restrict__ fuse, const float* __restrict__ w1,
    float* __restrict__ out_av, float* __restrict__ out_at,
    float* __restrict__ out_af, float* __restrict__ u1ws,
    float* __restrict__ scal) {
    int b = blockIdx.x, tid = threadIdx.x;
    __shared__ float Fv[32][33], Ft[32][33], Af[32][33], inv[64], wmax[4];
#pragma unroll
    for (int e = 0; e < 4; ++e) {
        int idx = tid + 256 * e;
        int i = idx >> 5, j = idx & 31;
        Fv[i][j] = fmaxf(fvp[b * 1024 + idx] + bv[j], 0.f);
        Ft[i][j] = fmaxf(ftp[b * 1024 + idx] + bt[j], 0.f);
    }
    __syncthreads();
    {
        int row = tid >> 3, cg = (tid & 7) * 4;
        float sv = 0.f, st = 0.f;
#pragma unroll
        for (int q = 0; q < 4; ++q) {
            float v = Fv[row][cg + q]; sv = fmaf(v, v, sv);
            float u = Ft[row][cg + q]; st = fmaf(u, u, st);
        }
        sv += __shfl_xor(sv, 1); sv += __shfl_xor(sv, 2); sv += __shfl_xor(sv, 4);
        st += __shfl_xor(st, 1); st += __shfl_xor(st, 2); st += __shfl_xor(st, 4);
        if ((tid & 7) == 0) {
            inv[row]      = rsqrtf(fmaxf(sv, 1e-24f));
            inv[32 + row] = rsqrtf(fmaxf(st, 1e-24f));
        }
    }
    __syncthreads();
    float fa[16];
#pragma unroll
    for (int q = 0; q < 16; ++q) fa[q] = fuse[q];
    float lmax = 0.f;
#pragma unroll
    for (int e = 0; e < 4; ++e) {
        int idx = tid + 256 * e;
        int i = idx >> 5, j = idx & 31;
        float dv = 0.f, dt_ = 0.f;
        for (int c = 0; c < 32; ++c) {
            dv  = fmaf(Fv[i][c], Fv[j][c], dv);
            dt_ = fmaf(Ft[i][c], Ft[j][c], dt_);
        }
        float av = fmaxf(dv  * inv[i] * inv[j], 0.f);
        float at = fmaxf(dt_ * inv[32 + i] * inv[32 + j], 0.f);
        out_av[b * 1024 + idx] = av;
        out_at[b * 1024 + idx] = at;
        float pv0 = (i == j) ? 1.f : 0.f;
        float pv1 = av, pv2 = av * av, pv3 = pv2 * av;
        float pt1 = at, pt2 = at * at, pt3 = pt2 * at;
        float af = 0.f;
        af += (fa[0] * pv0 + fa[4] * pv1 + fa[8]  * pv2 + fa[12] * pv3) * pv0;
        af += (fa[1] * pv0 + fa[5] * pv1 + fa[9]  * pv2 + fa[13] * pv3) * pt1;
        af += (fa[2] * pv0 + fa[6] * pv1 + fa[10] * pv2 + fa[14] * pv3) * pt2;
        af += (fa[3] * pv0 + fa[7] * pv1 + fa[11] * pv2 + fa[15] * pv3) * pt3;
        float r = fmaxf(af, 0.f);
        out_af[b * 1024 + idx] = r;   // pre-normalization; scaled in s4
        Af[i][j] = r;
        lmax = fmaxf(lmax, r);
    }
    for (int off = 1; off < 64; off <<= 1)
        lmax = fmaxf(lmax, __shfl_xor(lmax, off));
    if ((tid & 63) == 0) wmax[tid >> 6] = lmax;
    __syncthreads();   // Af complete + wmax visible
    if (tid == 0) {
        float mx = fmaxf(fmaxf(wmax[0], wmax[1]), fmaxf(wmax[2], wmax[3]));
        atomicMax((unsigned int*)scal, __float_as_uint(mx));  // values >= 0
    }
    // u1[b,o,l] = sum_c w1[o,c] * af_unscaled[b,l,c]; partial sums -> scal
    if (tid < 64) {
        int o = tid >> 5, l = tid & 31;
        float s = 0.f;
        for (int c = 0; c < 32; ++c) s = fmaf(w1[o * 32 + c], Af[l][c], s);
        u1ws[(size_t)(b * 2 + o) * 32 + l] = s;
        float s1 = s, s2 = s * s;
        for (int off = 1; off < 32; off <<= 1) {
            s1 += __shfl_xor(s1, off);
            s2 += __shfl_xor(s2, off);
        }
        if (l == 0) {
            atomicAdd(&scal[1 + o], s1);
            atomicAdd(&scal[3 + o], s2);
        }
    }
}

// Scale a_fused in place by inv=1/(max+0.01); BN1 (closed-form from u1
// sums: x1 = inv*u1 + b1 -> x1-mu = inv*(u1-m), var = inv^2*var_u; b1
// cancels) -> relu -> x2 = w2@h1 + b2; BN2 partial sums -> scal[5,6].
__global__ __launch_bounds__(256) void s4_kernel(
    float* __restrict__ af, const float* __restrict__ u1,
    const float* __restrict__ g1, const float* __restrict__ be1,
    const float* __restrict__ w2, const float* __restrict__ b2,
    float* __restrict__ x2, const float* __restrict__ scal) {
    int b = blockIdx.x, tid = threadIdx.x;
    float invs = 1.0f / (__uint_as_float(((const unsigned int*)scal)[0]) + 0.01f);
#pragma unroll
    for (int e = 0; e < 4; ++e) {
        int idx = tid + 256 * e;
        af[(size_t)b * 1024 + idx] *= invs;   // final a_fused output
    }
    if (tid < 32) {
        const float N = 20480.f;
        float m0 = scal[1] / N, m1 = scal[2] / N;
        float rs0 = rsqrtf(invs * invs * (scal[3] / N - m0 * m0) + 1e-5f);
        float rs1 = rsqrtf(invs * invs * (scal[4] / N - m1 * m1) + 1e-5f);
        float u0 = u1[(size_t)(b * 2 + 0) * 32 + tid];
        float u1v = u1[(size_t)(b * 2 + 1) * 32 + tid];
        float h0 = fmaxf(invs * (u0 - m0) * rs0 * g1[0] + be1[0], 0.f);
        float h1 = fmaxf(invs * (u1v - m1) * rs1 * g1[1] + be1[1], 0.f);
        float v = w2[0] * h0 + w2[1] * h1 + b2[0];
        x2[(size_t)b * 32 + tid] = v;
        float s1 = v, s2 = v * v;
        for (int off = 1; off < 32; off <<= 1) {
            s1 += __shfl_xor(s1, off);
            s2 += __shfl_xor(s2, off);
        }
        if (tid == 0) {
            atomicAdd((float*)&scal[5], s1);
            atomicAdd((float*)&scal[6], s2);
        }
    }
}

// BN2 -> relu -> sigmoid(w3*h2+b3) -> mean over 5 crops.
__global__ __launch_bounds__(256) void s5_kernel(
    const float* __restrict__ x2, const float* __restrict__ g2,
    const float* __restrict__ be2, const float* __restrict__ w3,
    const float* __restrict__ b3, float* __restrict__ ns,
    const float* __restrict__ scal) {
    int idx = blockIdx.x * 256 + threadIdx.x;   // 4096 = 128*32
    const float N = 20480.f;
    float mu = scal[5] / N;
    float var = scal[6] / N - mu * mu;
    float rs = rsqrtf(var + 1e-5f);
    int bb = idx >> 5, t = idx & 31;
    float s = 0.f;
#pragma unroll
    for (int crop = 0; crop < 5; ++crop) {
        int b = bb * 5 + crop;
        float h = fmaxf((x2[b * 32 + t] - mu) * rs * g2[0] + be2[0], 0.f);
        float z = w3[0] * h + b3[0];
        s += 1.f / (1.f + expf(-z));
    }
    ns[idx] = s * 0.2f;
}

extern "C" void kernel_launch(void* const* d_in, const int* in_sizes, int n_in,
                              void* d_out, int out_size, void* d_ws, size_t ws_size,
                              hipStream_t stream) {
    const float* v_feat = (const float*)d_in[0];
    const float* t_feat = (const float*)d_in[1];
    const float* wv  = (const float*)d_in[2];
    const float* bv  = (const float*)d_in[3];
    const float* wt  = (const float*)d_in[4];
    const float* bt  = (const float*)d_in[5];
    const float* fuse= (const float*)d_in[6];
    const float* w1  = (const float*)d_in[7];
    const float* b1  = (const float*)d_in[8];   // cancels in closed-form BN1
    const float* g1  = (const float*)d_in[9];
    const float* be1 = (const float*)d_in[10];
    const float* w2  = (const float*)d_in[11];
    const float* b2  = (const float*)d_in[12];
    const float* g2  = (const float*)d_in[13];
    const float* be2 = (const float*)d_in[14];
    const float* w3  = (const float*)d_in[15];
    const float* b3  = (const float*)d_in[16];
    (void)b1;

    float* ws   = (float*)d_ws;
    float* scal = ws;                       // [0]=max(uint), [1..4]=u1 S1/S2, [5..6]=BN2
    unsigned short* wvpk = (unsigned short*)(ws + 16);          // 393216 ushorts
    unsigned short* wtpk = (unsigned short*)(ws + 16 + 196608); // 147456 ushorts
    float* fv   = ws + 16 + 196608 + 73728; // 655360
    float* ft   = fv + 655360;              // 655360
    float* u1   = ft + 655360;              // 40960
    float* x2   = u1 + 40960;               // 20480

    float* out_ns = (float*)d_out;          // 4096
    float* out_av = out_ns + 4096;          // 655360
    float* out_at = out_av + 655360;        // 655360
    float* out_af = out_at + 655360;        // 655360

    pack_kernel<<<1056, 256, 0, stream>>>(wv, wt, wvpk, wtpk, scal, fv, ft);
    conv_mfma_kernel<<<2560, 256, 0, stream>>>(v_feat, wvpk, t_feat, wtpk, fv, ft);
    s2_kernel<<<640, 256, 0, stream>>>(fv, ft, bv, bt, fuse, w1, out_av, out_at,
                                       out_af, u1, scal);
    s4_kernel<<<640, 256, 0, stream>>>(out_af, u1, g1, be1, w2, b2, x2, scal);
    s5_kernel<<<16, 256, 0, stream>>>(x2, g2, be2, w3, b3, out_ns, scal);
}